// Round 10
// baseline (873.232 us; speedup 1.0000x reference)
//
#include <hip/hip_runtime.h>
#include <cstddef>

// DifferentiableRollout: x_{t+1} = x + DT * ( tanh([x,u]@W1 + b1) @ W2 + b2 )
// B=1024, T=200, SD=64, CD=32, H=512.  fp32 only (bf16 amplifies past the
// 1.245 absmax threshold; fp32 reorder noise alone is 0.25).
//
// History:
//  R5 (788us): weight preload arrays outside t-loop -> compiler remats as
//    just-in-time L2 loads.  Only no-spill/no-stall weight schedule found.
//  R8-R11: explicit residency/chunk/prefetch schemes -> scratch spill
//    (28 GB HBM, 8.5ms) or latency exposure (960-1045us).
//  R12 (707us, prev best): packed fp32 (v_pk_fma_f32) halved FMA issue.
//  R13 (828us, REGRESSION): W2->LDS + per-lane ks butterfly.  Falsified
//    "L2-BW-bound": stream 324->196 KB/step yet SLOWER.  Causes: xcT rows
//    (i,24+i,48+i,72+i at 16B/row) alias to same banks when ks is per-lane
//    -> 4-way conflict on every GEMM1 ds_read_b128; +16 shuffles/thread on
//    the LDS pipe.  Lesson: R12 is LATENCY-bound on remat L2 loads (64-VGPR
//    lookahead ~10 indep FMAs vs ~60 needed), not BW-bound.
//
// R14 (this round): R12 verbatim + W1 rows 0-47 LDS-resident.
//  - w1s[48][512] (98 KB) loaded once; waves with ks<2 (wave-uniform) read
//    weights as conflict-free lane-consecutive ds_read_b64 (128 contiguous
//    words/wave); ks>=2 waves keep the proven remat idiom.  Halves both the
//    latency-exposed L2 loads in GEMM1 and the stream (324->226 KB/step).
//  - xcT broadcast pattern untouched (ks stays wave-uniform = R12).
//  - reduce: 15-add serial chain -> pairwise tree (depth 4).
//  - LDS total 157,184 B (exact R8-R10 footprint, known to launch).
//  Verify: dur 590-650, LDS 157184, FETCH ~14 MB / WRITE ~51 MB (spill
//  tripwire), VGPR <= 64, absmax ~0.25.

constexpr int B_  = 1024;
constexpr int T_  = 200;
constexpr int SD_ = 64;
constexpr int CD_ = 32;
constexpr int H_  = 512;
constexpr int KD_ = SD_ + CD_;   // 96
constexpr float DT_ = 0.1f;
constexpr int ROWS_ = 4;
constexpr int THREADS_ = 1024;
constexpr int KSLICES_ = 4;      // GEMM1 K split (wave-uniform: tid>>8)
constexpr int KLEN_ = KD_ / KSLICES_;   // 24
constexpr int KLDS_ = 48;        // W1 rows resident in LDS (ks = 0,1)
constexpr int CHUNK_ = 32;       // W2 rows per wave (H / 16 waves)

typedef float f2 __attribute__((ext_vector_type(2)));

__global__ __launch_bounds__(THREADS_)
void rollout_r14_kernel(
    const float* __restrict__ x0,     // [B, SD]
    const float* __restrict__ ctrl,   // [B, T, CD]
    const float* __restrict__ W1,     // [KD, H]
    const float* __restrict__ b1,     // [H]
    const float* __restrict__ W2,     // [H, SD]
    const float* __restrict__ b2,     // [SD]
    float* __restrict__ out)          // [B, T+1, SD]
{
    __shared__ __align__(16) float w1s[KLDS_][H_];          // 98 KB: W1 rows 0-47
    __shared__ __align__(16) float xcT[KD_][ROWS_];         // state+control, transposed
    __shared__ __align__(16) float part1[KSLICES_][ROWS_][H_]; // GEMM1 partials, 32 KB
    __shared__ __align__(16) float pbuf[ROWS_][H_];         // tanh activations
    __shared__ __align__(16) float part2[ROWS_][16][SD_];   // GEMM2 partials

    const int tid = threadIdx.x;
    const int r0  = blockIdx.x * ROWS_;

    // ---- GEMM1 mapping: (ks = tid>>8 wave-uniform, jp = tid&255) ----
    const int jp    = tid & 255;        // j-pair index, j0 = 2*jp
    const int ks    = tid >> 8;         // 0..3 (wave-uniform)
    const int j0    = jp * 2;
    const int kbase = ks * KLEN_;

    // ks >= 2 waves: preload (compiler remats to JIT L2 loads -- R5/R12 idiom)
    f2 w1p[KLEN_];
    if (ks >= 2) {
        #pragma unroll
        for (int i = 0; i < KLEN_; ++i)
            w1p[i] = *(const f2*)&W1[(size_t)(kbase + i) * H_ + j0];
    }

    // ---- W1 rows 0-47 -> LDS (6 float4 per thread, coalesced) ----
    {
        const float4* __restrict__ src = (const float4*)W1;  // rows 0-47 contiguous
        float4* dst = (float4*)&w1s[0][0];
        #pragma unroll
        for (int i = 0; i < 6; ++i)
            dst[i * THREADS_ + tid] = src[i * THREADS_ + tid];
    }

    // ---- GEMM2 mapping: wave wv owns W2 rows [32wv,32wv+32), lane sl ----
    const int wv = tid >> 6;            // 0..15 (wave id)
    const int sl = tid & 63;
    const int jb = wv * CHUNK_;
    float w2p[CHUNK_];
    #pragma unroll
    for (int i = 0; i < CHUNK_; ++i)
        w2p[i] = W2[(size_t)(jb + i) * SD_ + sl];        // remat idiom

    // ---- finish mapping: (rF, jjF pair) ----
    const int rF  = tid >> 8;           // 0..3
    const int jjF = (tid & 255) * 2;
    const f2 bj2 = {b1[jjF], b1[jjF + 1]};

    // reduce/update mapping (tid < 256)
    const int rf = (tid >> 6) & 3;
    const int sf = tid & 63;
    const float bs = b2[sf];

    // ctrl loader: tids [512, 640)
    const int  lt = tid - 512;
    const bool loader = (lt >= 0) && (lt < ROWS_ * CD_);
    const int  lr = (lt >> 5) & 3;
    const int  lc = lt & 31;
    const size_t ctrl_base = (size_t)(r0 + lr) * T_ * CD_ + lc;

    // ---- init: x0 into xcT + states[:,0,:], ctrl[0] into xcT ----
    if (tid < ROWS_ * SD_) {
        const float v = x0[(size_t)(r0 + rf) * SD_ + sf];
        xcT[sf][rf] = v;
        out[(size_t)(r0 + rf) * (T_ + 1) * SD_ + sf] = v;
    }
    if (loader) xcT[SD_ + lc][lr] = ctrl[ctrl_base];
    __syncthreads();   // covers xcT init AND w1s copy

    for (int t = 0; t < T_; ++t) {
        // ---- prefetch next step's controls into a register ----
        float cpre = 0.f;
        if (loader && (t + 1 < T_))
            cpre = ctrl[ctrl_base + (size_t)(t + 1) * CD_];

        // ---- GEMM1 rank-24 partials: 4 rows x j-pair, packed fp32 ----
        f2 a0 = {0.f, 0.f}, a1 = {0.f, 0.f}, a2 = {0.f, 0.f}, a3 = {0.f, 0.f};
        if (ks < 2) {
            // weights from LDS: lane-consecutive b64, conflict-free
            #pragma unroll
            for (int i = 0; i < KLEN_; ++i) {
                const float4 xv = *(const float4*)&xcT[kbase + i][0];  // broadcast
                const f2 w = *(const f2*)&w1s[kbase + i][j0];
                a0 = __builtin_elementwise_fma(w, (f2){xv.x, xv.x}, a0);
                a1 = __builtin_elementwise_fma(w, (f2){xv.y, xv.y}, a1);
                a2 = __builtin_elementwise_fma(w, (f2){xv.z, xv.z}, a2);
                a3 = __builtin_elementwise_fma(w, (f2){xv.w, xv.w}, a3);
            }
        } else {
            // weights remat-streamed from L2 (R5/R12 idiom)
            #pragma unroll
            for (int i = 0; i < KLEN_; ++i) {
                const float4 xv = *(const float4*)&xcT[kbase + i][0];  // broadcast
                const f2 w = w1p[i];
                a0 = __builtin_elementwise_fma(w, (f2){xv.x, xv.x}, a0);
                a1 = __builtin_elementwise_fma(w, (f2){xv.y, xv.y}, a1);
                a2 = __builtin_elementwise_fma(w, (f2){xv.z, xv.z}, a2);
                a3 = __builtin_elementwise_fma(w, (f2){xv.w, xv.w}, a3);
            }
        }
        *(f2*)&part1[ks][0][j0] = a0;
        *(f2*)&part1[ks][1][j0] = a1;
        *(f2*)&part1[ks][2][j0] = a2;
        *(f2*)&part1[ks][3][j0] = a3;
        __syncthreads();   // A: part1 visible; all step-t xcT reads done

        // ---- finish: sum 4 slices + bias, tanh x2, all threads ----
        {
            f2 s = *(const f2*)&part1[0][rF][jjF];
            s += *(const f2*)&part1[1][rF][jjF];
            s += *(const f2*)&part1[2][rF][jjF];
            s += *(const f2*)&part1[3][rF][jjF];
            s += bj2;
            f2 hv;
            hv.x = tanhf(s.x);
            hv.y = tanhf(s.y);
            *(f2*)&pbuf[rF][jjF] = hv;
            if (loader && (t + 1 < T_))
                xcT[SD_ + lc][lr] = cpre;   // step-t xcT reads done at A
        }
        __syncthreads();   // B: activations visible

        // ---- GEMM2: wave wv, h in [jb, jb+32), packed along H ----
        {
            f2 q0 = {0.f, 0.f}, q1 = {0.f, 0.f}, q2 = {0.f, 0.f}, q3 = {0.f, 0.f};
            #pragma unroll
            for (int i4 = 0; i4 < CHUNK_; i4 += 4) {
                const f2 wab = {w2p[i4 + 0], w2p[i4 + 1]};
                const f2 wcd = {w2p[i4 + 2], w2p[i4 + 3]};
                const float4 h0 = *(const float4*)&pbuf[0][jb + i4];  // broadcast
                const float4 h1 = *(const float4*)&pbuf[1][jb + i4];
                const float4 h2 = *(const float4*)&pbuf[2][jb + i4];
                const float4 h3 = *(const float4*)&pbuf[3][jb + i4];
                q0 = __builtin_elementwise_fma((f2){h0.x, h0.y}, wab, q0);
                q0 = __builtin_elementwise_fma((f2){h0.z, h0.w}, wcd, q0);
                q1 = __builtin_elementwise_fma((f2){h1.x, h1.y}, wab, q1);
                q1 = __builtin_elementwise_fma((f2){h1.z, h1.w}, wcd, q1);
                q2 = __builtin_elementwise_fma((f2){h2.x, h2.y}, wab, q2);
                q2 = __builtin_elementwise_fma((f2){h2.z, h2.w}, wcd, q2);
                q3 = __builtin_elementwise_fma((f2){h3.x, h3.y}, wab, q3);
                q3 = __builtin_elementwise_fma((f2){h3.z, h3.w}, wcd, q3);
            }
            part2[0][wv][sl] = q0.x + q0.y;   // lane-consecutive: conflict-free
            part2[1][wv][sl] = q1.x + q1.y;
            part2[2][wv][sl] = q2.x + q2.y;
            part2[3][wv][sl] = q3.x + q3.y;
        }
        __syncthreads();   // C: part2 visible

        // ---- pairwise-tree reduce + state update: tid < 256 ----
        if (tid < ROWS_ * SD_) {
            float v[16];
            #pragma unroll
            for (int c = 0; c < 16; ++c) v[c] = part2[rf][c][sf];
            const float s0 = (v[0] + v[1]) + (v[2] + v[3]);
            const float s1 = (v[4] + v[5]) + (v[6] + v[7]);
            const float s2 = (v[8] + v[9]) + (v[10] + v[11]);
            const float s3 = (v[12] + v[13]) + (v[14] + v[15]);
            const float acc = (s0 + s1) + (s2 + s3);
            const float xnew = xcT[sf][rf] + DT_ * (acc + bs);
            xcT[sf][rf] = xnew;
            out[(size_t)(r0 + rf) * (T_ + 1) * SD_ + (size_t)(t + 1) * SD_ + sf] = xnew;
        }
        __syncthreads();   // D: new state visible; part2/pbuf reads done
    }
}

extern "C" void kernel_launch(void* const* d_in, const int* in_sizes, int n_in,
                              void* d_out, int out_size, void* d_ws, size_t ws_size,
                              hipStream_t stream) {
    const float* x0   = (const float*)d_in[0];
    const float* ctrl = (const float*)d_in[1];
    const float* W1   = (const float*)d_in[2];
    const float* b1   = (const float*)d_in[3];
    const float* W2   = (const float*)d_in[4];
    const float* b2   = (const float*)d_in[5];
    float* out = (float*)d_out;

    dim3 grid(B_ / ROWS_);      // 256 blocks -> 1 per CU (persistent)
    dim3 block(THREADS_);
    rollout_r14_kernel<<<grid, block, 0, stream>>>(x0, ctrl, W1, b1, W2, b2, out);
}

// Round 11
// 664.231 us; speedup vs baseline: 1.3147x; 1.3147x over previous
//
#include <hip/hip_runtime.h>
#include <cstddef>

// DifferentiableRollout: x_{t+1} = x + DT * ( tanh([x,u]@W1 + b1) @ W2 + b2 )
// B=1024, T=200, SD=64, CD=32, H=512.  fp32 only.
//
// History (counters-driven):
//  R5 788us: weight preload arrays -> compiler JIT-remat from L2. VALU 77%.
//  R8-R11: explicit residency/prefetch -> scratch spill or latency exposure.
//  R12 707us (prev best): packed fp32 v_pk_fma halved FMA issue. VALU 51%.
//  R13 828us / R14 873us: moving weights INTO LDS regressed BOTH times.
//    => falsifies L2-BW and L2-latency theories.  The kernel is LDS-DATA-
//    RETURN bound: wave-broadcast ds_read_b128 still costs ~8-12 cyc/instr
//    (m134).  R12 audit: 384 xcT b128 + 512 pbuf b128 + writes ~ 9000 cyc
//    of LDS pipe per step ~ the measured 8820 cyc/step.
//
// R15 (this round): halve broadcast-read instructions; weights stay in L2
//  (R12's exact remat idiom, identical 80-float demand, identical bytes).
//  - GEMM1: KSLICES 4->8 (KLEN=12), thread owns TWO j-pairs (j0, j0+256).
//    Same 96 pk_fma, xcT reads 24->12 per thread (384->192 wave-instrs).
//    part1 grows to [8][4][512] (64 KB); finish sums 8 slices (tree).
//  - GEMM2: lane=(l5,sfp): sf-PAIR per lane, l5 splits the wave's 32-h
//    chunk (2-addr broadcast = free, m136).  Same 64 pk_fma, W2 as 16 f2
//    loads (same bytes, half the instrs), pbuf reads 32->16 per thread
//    (512->256 wave-instrs).  part2 [4][32][64], 32-way tree reduce.
//  LDS: 64K part1 + 32K part2 + 8K pbuf + 1.5K xcT = 105.5 KB.
//  Verify: dur 560-630, LDS ~108K, VALU 58-68%, FETCH ~14.4 MB /
//  WRITE ~51.5 MB / VGPR 56-64 (spill tripwire), absmax 0.25.

constexpr int B_  = 1024;
constexpr int T_  = 200;
constexpr int SD_ = 64;
constexpr int CD_ = 32;
constexpr int H_  = 512;
constexpr int KD_ = SD_ + CD_;   // 96
constexpr float DT_ = 0.1f;
constexpr int ROWS_ = 4;
constexpr int THREADS_ = 1024;
constexpr int KSLICES_ = 8;      // GEMM1 K split (wave-uniform: tid>>7)
constexpr int KLEN_ = KD_ / KSLICES_;   // 12

typedef float f2 __attribute__((ext_vector_type(2)));

__global__ __launch_bounds__(THREADS_)
void rollout_r15_kernel(
    const float* __restrict__ x0,     // [B, SD]
    const float* __restrict__ ctrl,   // [B, T, CD]
    const float* __restrict__ W1,     // [KD, H]
    const float* __restrict__ b1,     // [H]
    const float* __restrict__ W2,     // [H, SD]
    const float* __restrict__ b2,     // [SD]
    float* __restrict__ out)          // [B, T+1, SD]
{
    __shared__ __align__(16) float xcT[KD_][ROWS_];            // 1.5 KB
    __shared__ __align__(16) float part1[KSLICES_][ROWS_][H_]; // 64 KB
    __shared__ __align__(16) float pbuf[ROWS_][H_];            // 8 KB
    __shared__ __align__(16) float part2[ROWS_][32][SD_];      // 32 KB

    const int tid = threadIdx.x;
    const int r0  = blockIdx.x * ROWS_;

    // ---- GEMM1 mapping: (ks = tid>>7 wave-uniform, jpg = tid&127) ----
    // thread owns j-pairs {2*jpg, 2*jpg+1} and {2*jpg+256, 2*jpg+257}
    const int jpg   = tid & 127;
    const int ks    = tid >> 7;         // 0..7 (wave-uniform: 2 waves/slice)
    const int j0    = jpg * 2;
    const int kbase = ks * KLEN_;
    f2 w1a[KLEN_], w1b[KLEN_];          // preload -> compiler remats (R5/R12 idiom)
    #pragma unroll
    for (int i = 0; i < KLEN_; ++i) {
        w1a[i] = *(const f2*)&W1[(size_t)(kbase + i) * H_ + j0];
        w1b[i] = *(const f2*)&W1[(size_t)(kbase + i) * H_ + j0 + 256];
    }

    // ---- GEMM2 mapping: wave wv, lane = (l5, sfp) ----
    // lane covers sf-pair {2sfp, 2sfp+1}; l5 selects h-half of the chunk
    const int wv    = tid >> 6;         // 0..15
    const int lane  = tid & 63;
    const int l5    = lane >> 5;        // 0,1
    const int sfp   = lane & 31;
    const int sf0   = sfp * 2;
    const int hbase = wv * 32 + l5 * 16;
    f2 w2p[16];                         // preload -> remat (same bytes as R12)
    #pragma unroll
    for (int i = 0; i < 16; ++i)
        w2p[i] = *(const f2*)&W2[(size_t)(hbase + i) * SD_ + sf0];

    // ---- finish mapping: (rF, jjF pair) ----
    const int rF  = tid >> 8;           // 0..3
    const int jjF = (tid & 255) * 2;
    const f2 bj2 = {b1[jjF], b1[jjF + 1]};

    // reduce/update mapping (tid < 256)
    const int rf = (tid >> 6) & 3;
    const int sf = tid & 63;
    const float bs = b2[sf];

    // ctrl loader: tids [512, 640)
    const int  lt = tid - 512;
    const bool loader = (lt >= 0) && (lt < ROWS_ * CD_);
    const int  lr = (lt >> 5) & 3;
    const int  lc = lt & 31;
    const size_t ctrl_base = (size_t)(r0 + lr) * T_ * CD_ + lc;

    // ---- init: x0 into xcT + states[:,0,:], ctrl[0] into xcT ----
    if (tid < ROWS_ * SD_) {
        const float v = x0[(size_t)(r0 + rf) * SD_ + sf];
        xcT[sf][rf] = v;
        out[(size_t)(r0 + rf) * (T_ + 1) * SD_ + sf] = v;
    }
    if (loader) xcT[SD_ + lc][lr] = ctrl[ctrl_base];
    __syncthreads();

    for (int t = 0; t < T_; ++t) {
        // ---- prefetch next step's controls into a register ----
        float cpre = 0.f;
        if (loader && (t + 1 < T_))
            cpre = ctrl[ctrl_base + (size_t)(t + 1) * CD_];

        // ---- GEMM1 rank-12 partials: 4 rows x TWO j-pairs per thread ----
        f2 a0 = {0.f,0.f}, a1 = {0.f,0.f}, a2 = {0.f,0.f}, a3 = {0.f,0.f};
        f2 b0 = {0.f,0.f}, b1v = {0.f,0.f}, b2v = {0.f,0.f}, b3 = {0.f,0.f};
        #pragma unroll
        for (int i = 0; i < KLEN_; ++i) {
            const float4 xv = *(const float4*)&xcT[kbase + i][0];  // 1-addr bcast
            const f2 wa = w1a[i];
            const f2 wb = w1b[i];
            a0  = __builtin_elementwise_fma(wa, (f2){xv.x, xv.x}, a0);
            a1  = __builtin_elementwise_fma(wa, (f2){xv.y, xv.y}, a1);
            a2  = __builtin_elementwise_fma(wa, (f2){xv.z, xv.z}, a2);
            a3  = __builtin_elementwise_fma(wa, (f2){xv.w, xv.w}, a3);
            b0  = __builtin_elementwise_fma(wb, (f2){xv.x, xv.x}, b0);
            b1v = __builtin_elementwise_fma(wb, (f2){xv.y, xv.y}, b1v);
            b2v = __builtin_elementwise_fma(wb, (f2){xv.z, xv.z}, b2v);
            b3  = __builtin_elementwise_fma(wb, (f2){xv.w, xv.w}, b3);
        }
        *(f2*)&part1[ks][0][j0] = a0;
        *(f2*)&part1[ks][1][j0] = a1;
        *(f2*)&part1[ks][2][j0] = a2;
        *(f2*)&part1[ks][3][j0] = a3;
        *(f2*)&part1[ks][0][j0 + 256] = b0;
        *(f2*)&part1[ks][1][j0 + 256] = b1v;
        *(f2*)&part1[ks][2][j0 + 256] = b2v;
        *(f2*)&part1[ks][3][j0 + 256] = b3;
        __syncthreads();   // A: part1 visible; all step-t xcT reads done

        // ---- finish: tree-sum 8 slices + bias, tanh x2, all threads ----
        {
            const f2 s0 = *(const f2*)&part1[0][rF][jjF] + *(const f2*)&part1[1][rF][jjF];
            const f2 s1 = *(const f2*)&part1[2][rF][jjF] + *(const f2*)&part1[3][rF][jjF];
            const f2 s2 = *(const f2*)&part1[4][rF][jjF] + *(const f2*)&part1[5][rF][jjF];
            const f2 s3 = *(const f2*)&part1[6][rF][jjF] + *(const f2*)&part1[7][rF][jjF];
            const f2 s  = ((s0 + s1) + (s2 + s3)) + bj2;
            f2 hv;
            hv.x = tanhf(s.x);
            hv.y = tanhf(s.y);
            *(f2*)&pbuf[rF][jjF] = hv;
            if (loader && (t + 1 < T_))
                xcT[SD_ + lc][lr] = cpre;   // step-t xcT reads done at A
        }
        __syncthreads();   // B: activations visible

        // ---- GEMM2: wave wv, lane's 16-h half-chunk, sf-pair wide ----
        {
            f2 q0 = {0.f,0.f}, q1 = {0.f,0.f}, q2 = {0.f,0.f}, q3 = {0.f,0.f};
            #pragma unroll
            for (int i4 = 0; i4 < 16; i4 += 4) {
                const float4 h0 = *(const float4*)&pbuf[0][hbase + i4]; // 2-addr bcast (free)
                const float4 h1 = *(const float4*)&pbuf[1][hbase + i4];
                const float4 h2 = *(const float4*)&pbuf[2][hbase + i4];
                const float4 h3 = *(const float4*)&pbuf[3][hbase + i4];
                q0 = __builtin_elementwise_fma((f2){h0.x, h0.x}, w2p[i4 + 0], q0);
                q0 = __builtin_elementwise_fma((f2){h0.y, h0.y}, w2p[i4 + 1], q0);
                q0 = __builtin_elementwise_fma((f2){h0.z, h0.z}, w2p[i4 + 2], q0);
                q0 = __builtin_elementwise_fma((f2){h0.w, h0.w}, w2p[i4 + 3], q0);
                q1 = __builtin_elementwise_fma((f2){h1.x, h1.x}, w2p[i4 + 0], q1);
                q1 = __builtin_elementwise_fma((f2){h1.y, h1.y}, w2p[i4 + 1], q1);
                q1 = __builtin_elementwise_fma((f2){h1.z, h1.z}, w2p[i4 + 2], q1);
                q1 = __builtin_elementwise_fma((f2){h1.w, h1.w}, w2p[i4 + 3], q1);
                q2 = __builtin_elementwise_fma((f2){h2.x, h2.x}, w2p[i4 + 0], q2);
                q2 = __builtin_elementwise_fma((f2){h2.y, h2.y}, w2p[i4 + 1], q2);
                q2 = __builtin_elementwise_fma((f2){h2.z, h2.z}, w2p[i4 + 2], q2);
                q2 = __builtin_elementwise_fma((f2){h2.w, h2.w}, w2p[i4 + 3], q2);
                q3 = __builtin_elementwise_fma((f2){h3.x, h3.x}, w2p[i4 + 0], q3);
                q3 = __builtin_elementwise_fma((f2){h3.y, h3.y}, w2p[i4 + 1], q3);
                q3 = __builtin_elementwise_fma((f2){h3.z, h3.z}, w2p[i4 + 2], q3);
                q3 = __builtin_elementwise_fma((f2){h3.w, h3.w}, w2p[i4 + 3], q3);
            }
            const int c = wv * 2 + l5;          // 0..31
            *(f2*)&part2[0][c][sf0] = q0;       // 2-way bank use: free
            *(f2*)&part2[1][c][sf0] = q1;
            *(f2*)&part2[2][c][sf0] = q2;
            *(f2*)&part2[3][c][sf0] = q3;
        }
        __syncthreads();   // C: part2 visible

        // ---- 32-way tree reduce + state update: tid < 256 ----
        if (tid < ROWS_ * SD_) {
            float v[32];
            #pragma unroll
            for (int c = 0; c < 32; ++c) v[c] = part2[rf][c][sf];
            float s[8];
            #pragma unroll
            for (int c = 0; c < 8; ++c)
                s[c] = (v[4*c] + v[4*c+1]) + (v[4*c+2] + v[4*c+3]);
            const float acc = ((s[0] + s[1]) + (s[2] + s[3]))
                            + ((s[4] + s[5]) + (s[6] + s[7]));
            const float xnew = xcT[sf][rf] + DT_ * (acc + bs);
            xcT[sf][rf] = xnew;
            out[(size_t)(r0 + rf) * (T_ + 1) * SD_ + (size_t)(t + 1) * SD_ + sf] = xnew;
        }
        __syncthreads();   // D: new state visible; part2/pbuf reads done
    }
}

extern "C" void kernel_launch(void* const* d_in, const int* in_sizes, int n_in,
                              void* d_out, int out_size, void* d_ws, size_t ws_size,
                              hipStream_t stream) {
    const float* x0   = (const float*)d_in[0];
    const float* ctrl = (const float*)d_in[1];
    const float* W1   = (const float*)d_in[2];
    const float* b1   = (const float*)d_in[3];
    const float* W2   = (const float*)d_in[4];
    const float* b2   = (const float*)d_in[5];
    float* out = (float*)d_out;

    dim3 grid(B_ / ROWS_);      // 256 blocks -> 1 per CU (persistent)
    dim3 block(THREADS_);
    rollout_r15_kernel<<<grid, block, 0, stream>>>(x0, ctrl, W1, b1, W2, b2, out);
}